// Round 4
// baseline (450.020 us; speedup 1.0000x reference)
//
#include <hip/hip_runtime.h>
#include <hip/hip_bf16.h>
#include <hip/hip_fp8.h>
#include <stdint.h>
#include <math.h>

#define NROWS 16384
#define DHALF 384
#define DFULL 768
#define EPSF  1e-8f
#define QSCALE 64.0f   // power-of-2: lossless rel-err shift into e4m3 normal range

typedef __attribute__((ext_vector_type(4))) float f32x4;
typedef __attribute__((ext_vector_type(4))) int   int4v;
typedef __attribute__((ext_vector_type(8))) int   int8v;

// ---- async global->LDS, 16B per lane (wave-uniform base + lane*16) ----
__device__ __forceinline__ void async_copy16(const void* gptr, void* lptr) {
    __builtin_amdgcn_global_load_lds(
        (const __attribute__((address_space(1))) unsigned int*)gptr,
        (__attribute__((address_space(3))) unsigned int*)lptr,
        16, 0, 0);
}

__device__ __forceinline__ unsigned long long pack_key(float v, int idx) {
    unsigned u = __float_as_uint(v);
    u = (u & 0x80000000u) ? ~u : (u | 0x80000000u);  // monotone float->u32
    return ((unsigned long long)u << 32) | (unsigned)idx;
}

// ---------------------------------------------------------------------
// Kernel 0: zero best[] (argmax accumulator)
// ---------------------------------------------------------------------
__global__ void init_kernel(unsigned long long* __restrict__ best) {
    int i = blockIdx.x * blockDim.x + threadIdx.x;
    if (i < NROWS) best[i] = 0ull;
}

// ---------------------------------------------------------------------
// Kernel 1: per-row L2 norm over concat(a,b); write fp8-e4m3 of
// (x_norm * 64) for the scale-invariant argmax GEMM. fp32 invn kept.
// ---------------------------------------------------------------------
__global__ __launch_bounds__(256) void normalize_kernel(
    const float* __restrict__ a, const float* __restrict__ b,
    unsigned char* __restrict__ xq, float* __restrict__ invn) {
    int wave = threadIdx.x >> 6;
    int lane = threadIdx.x & 63;
    int row  = blockIdx.x * 4 + wave;

    const float* pa = a + (size_t)row * DHALF;
    const float* pb = b + (size_t)row * DHALF;

    float va[6], vb[6];
    float s = 0.0f;
#pragma unroll
    for (int it = 0; it < 6; ++it) { va[it] = pa[lane + 64 * it]; s += va[it] * va[it]; }
#pragma unroll
    for (int it = 0; it < 6; ++it) { vb[it] = pb[lane + 64 * it]; s += vb[it] * vb[it]; }
#pragma unroll
    for (int d = 1; d < 64; d <<= 1) s += __shfl_xor(s, d, 64);

    float inv = 1.0f / fmaxf(sqrtf(s), EPSF);
    if (lane == 0) invn[row] = inv;
    float qs = inv * QSCALE;

    unsigned char* px = xq + (size_t)row * DFULL;
#pragma unroll
    for (int it = 0; it < 6; ++it) {
        __hip_fp8_e4m3 q(va[it] * qs);
        px[lane + 64 * it] = q.__x;
    }
#pragma unroll
    for (int it = 0; it < 6; ++it) {
        __hip_fp8_e4m3 q(vb[it] * qs);
        px[DHALF + lane + 64 * it] = q.__x;
    }
}

// ---------------------------------------------------------------------
// Kernel 2: scaled dots = (64x)·(64x)^T via MX-fp8 K=128 MFMA,
// upper-triangle tile-blocks (symmetry), 128x128 tile, BK=128,
// XOR-swizzled LDS granules (conflict-free). Row+col argmax, diag masked.
// Dots are scaled by 4096 — argmax is scale-invariant.
// ---------------------------------------------------------------------
__global__ __launch_bounds__(256) void argmax_kernel(
    const unsigned char* __restrict__ xq,
    unsigned long long* __restrict__ best) {
    __shared__ unsigned char As[128 * 128];
    __shared__ unsigned char Bs[128 * 128];

    // decode upper-triangle pair: k -> (rb <= cb)
    int k = blockIdx.x;
    int i = (int)((sqrtf(8.0f * (float)k + 1.0f) - 1.0f) * 0.5f);
    while ((i + 1) * (i + 2) / 2 <= k) ++i;
    while (i * (i + 1) / 2 > k) --i;
    int cb = i;
    int rb = k - i * (i + 1) / 2;   // rb <= cb
    int r0 = rb * 128, c0 = cb * 128;

    int tid  = threadIdx.x;
    int wave = tid >> 6, lane = tid & 63;
    int wr = wave >> 1, wc = wave & 1;
    int quad = lane >> 4, l15 = lane & 15;

    f32x4 acc[4][4] = {};
    const int SC = 0x7f7f7f7f;      // e8m0 scales = 1.0 in every byte

    for (int k0 = 0; k0 < DFULL; k0 += 128) {
        // stage [128 rows][128 bytes] per matrix; granule g of row r
        // stored at slot g^(r&7)  (16B granules, 8 slots/row)
#pragma unroll
        for (int round = 0; round < 4; ++round) {
            int idx = round * 256 + tid;       // 0..1023
            int r   = idx >> 3;                // 0..127
            int gs  = ((idx & 7) ^ (r & 7)) << 4;
            async_copy16(xq + (size_t)(r0 + r) * DFULL + k0 + gs, &As[idx * 16]);
            async_copy16(xq + (size_t)(c0 + r) * DFULL + k0 + gs, &Bs[idx * 16]);
        }
        __syncthreads();

        // fragment: row = l15 (+tile), k-bytes quad*32..+31 = granules 2q,2q+1
        int s0 = (((quad << 1) ^ (l15 & 7)) << 4);
        int s1 = s0 ^ 16;

        union Frag { int4v q[2]; int8v o; };
        Frag bfr[4];
#pragma unroll
        for (int t = 0; t < 4; ++t) {
            const unsigned char* rp = &Bs[(wc * 64 + t * 16 + l15) * 128];
            bfr[t].q[0] = *(const int4v*)(rp + s0);
            bfr[t].q[1] = *(const int4v*)(rp + s1);
        }
#pragma unroll
        for (int ti = 0; ti < 4; ++ti) {
            Frag afr;
            const unsigned char* rp = &As[(wr * 64 + ti * 16 + l15) * 128];
            afr.q[0] = *(const int4v*)(rp + s0);
            afr.q[1] = *(const int4v*)(rp + s1);
#pragma unroll
            for (int tj = 0; tj < 4; ++tj)
                acc[ti][tj] = __builtin_amdgcn_mfma_scale_f32_16x16x128_f8f6f4(
                    afr.o, bfr[tj].o, acc[ti][tj], 0, 0, 0, SC, 0, SC);
        }
        __syncthreads();
    }

    int rbase = r0 + wr * 64, cbase = c0 + wc * 64;

    // Row-direction: best over this block's 128 columns, diag masked.
    // NOTE: scaled dots span ~±4096 — init must be below all finite dots.
#pragma unroll
    for (int ti = 0; ti < 4; ++ti) {
#pragma unroll
        for (int reg = 0; reg < 4; ++reg) {
            int grow = rbase + ti * 16 + quad * 4 + reg;
            float bv = -3.0e38f; int bc = 0;
#pragma unroll
            for (int tj = 0; tj < 4; ++tj) {
                float v   = acc[ti][tj][reg];
                int  gcol = cbase + tj * 16 + l15;
                if (gcol == grow) v = -1.0e30f;   // diagonal mask
                if (v > bv) { bv = v; bc = gcol; }
            }
#pragma unroll
            for (int d = 1; d < 16; d <<= 1) {
                float ov = __shfl_xor(bv, d, 64);
                int   oc = __shfl_xor(bc, d, 64);
                if (ov > bv) { bv = ov; bc = oc; }
            }
            if (l15 == 0) atomicMax(&best[grow], pack_key(bv, bc));
        }
    }

    // Column-direction (off-diagonal blocks): best over this block's 128 rows
    if (rb != cb) {
#pragma unroll
        for (int tj = 0; tj < 4; ++tj) {
            float bv = -3.0e38f; int br = 0;
#pragma unroll
            for (int ti = 0; ti < 4; ++ti)
#pragma unroll
                for (int reg = 0; reg < 4; ++reg) {
                    float v = acc[ti][tj][reg];
                    int grow = rbase + ti * 16 + quad * 4 + reg;
                    if (v > bv) { bv = v; br = grow; }
                }
#pragma unroll
            for (int d = 16; d < 64; d <<= 1) {
                float ov = __shfl_xor(bv, d, 64);
                int   orr = __shfl_xor(br, d, 64);
                if (ov > bv) { bv = ov; br = orr; }
            }
            if (quad == 0) {
                int gcol = cbase + tj * 16 + l15;
                atomicMax(&best[gcol], pack_key(bv, br));
            }
        }
    }
}

// ---------------------------------------------------------------------
// Kernel 3: per-row term = log(||xn_i - xn_j + eps|| + eps), fp32 from
// original inputs. One wave per row. NO atomics — coalesced store.
// ---------------------------------------------------------------------
__global__ __launch_bounds__(256) void loss_kernel(
    const float* __restrict__ a, const float* __restrict__ b,
    const float* __restrict__ invn,
    const unsigned long long* __restrict__ best,
    float* __restrict__ terms) {
    int wave = threadIdx.x >> 6;
    int lane = threadIdx.x & 63;
    int row  = blockIdx.x * 4 + wave;

    int j = (int)(best[row] & 0xffffffffull);
    float ii = invn[row], ij = invn[j];

    const float* pai = a + (size_t)row * DHALF;
    const float* pbi = b + (size_t)row * DHALF;
    const float* paj = a + (size_t)j * DHALF;
    const float* pbj = b + (size_t)j * DHALF;

    float s = 0.0f;
#pragma unroll
    for (int it = 0; it < 6; ++it) {
        int kk = lane + 64 * it;
        float d = pai[kk] * ii - paj[kk] * ij + EPSF;
        s += d * d;
    }
#pragma unroll
    for (int it = 0; it < 6; ++it) {
        int kk = lane + 64 * it;
        float d = pbi[kk] * ii - pbj[kk] * ij + EPSF;
        s += d * d;
    }
#pragma unroll
    for (int d = 1; d < 64; d <<= 1) s += __shfl_xor(s, d, 64);

    if (lane == 0) terms[row] = logf(sqrtf(s) + EPSF);
}

// ---------------------------------------------------------------------
// Kernel 4: single-block tree reduction of terms -> out[0] = -mean
// ---------------------------------------------------------------------
__global__ __launch_bounds__(1024) void reduce_kernel(
    const float* __restrict__ terms, float* __restrict__ out) {
    __shared__ float partial[16];
    int tid = threadIdx.x;
    float s = 0.0f;
#pragma unroll
    for (int it = 0; it < NROWS / 1024; ++it) s += terms[tid + 1024 * it];
#pragma unroll
    for (int d = 1; d < 64; d <<= 1) s += __shfl_xor(s, d, 64);
    if ((tid & 63) == 0) partial[tid >> 6] = s;
    __syncthreads();
    if (tid < 16) {
        s = partial[tid];
#pragma unroll
        for (int d = 1; d < 16; d <<= 1) s += __shfl_xor(s, d, 16);
        if (tid == 0) out[0] = -s * (1.0f / (float)NROWS);
    }
}

// ---------------------------------------------------------------------
extern "C" void kernel_launch(void* const* d_in, const int* in_sizes, int n_in,
                              void* d_out, int out_size, void* d_ws, size_t ws_size,
                              hipStream_t stream) {
    const float* a = (const float*)d_in[0];
    const float* b = (const float*)d_in[1];
    float* out = (float*)d_out;

    char* ws = (char*)d_ws;
    unsigned char* xq = (unsigned char*)ws;                                    // 12582912 B
    unsigned long long* best = (unsigned long long*)(ws + 12582912);           // 131072 B
    float* invn  = (float*)(ws + 12582912 + 131072);                           // 65536 B
    float* terms = (float*)(ws + 12582912 + 131072 + 65536);                   // 65536 B

    const int NTILE = NROWS / 128;                     // 128
    const int NBLK  = NTILE * (NTILE + 1) / 2;         // 8256

    init_kernel<<<NROWS / 256, 256, 0, stream>>>(best);
    normalize_kernel<<<NROWS / 4, 256, 0, stream>>>(a, b, xq, invn);
    argmax_kernel<<<NBLK, 256, 0, stream>>>(xq, best);
    loss_kernel<<<NROWS / 4, 256, 0, stream>>>(a, b, invn, best, terms);
    reduce_kernel<<<1, 1024, 0, stream>>>(terms, out);
}

// Round 5
// 287.687 us; speedup vs baseline: 1.5643x; 1.5643x over previous
//
#include <hip/hip_runtime.h>
#include <hip/hip_bf16.h>
#include <hip/hip_fp8.h>
#include <stdint.h>
#include <math.h>

#define NROWS 16384
#define DHALF 384
#define DFULL 768
#define EPSF  1e-8f
#define QSCALE 64.0f   // power-of-2: lossless rel-err shift into e4m3 normal range

typedef __attribute__((ext_vector_type(4))) float f32x4;
typedef __attribute__((ext_vector_type(4))) int   int4v;
typedef __attribute__((ext_vector_type(8))) int   int8v;

// ---- async global->LDS, 16B per lane (wave-uniform base + lane*16) ----
__device__ __forceinline__ void async_copy16(const void* gptr, void* lptr) {
    __builtin_amdgcn_global_load_lds(
        (const __attribute__((address_space(1))) unsigned int*)gptr,
        (__attribute__((address_space(3))) unsigned int*)lptr,
        16, 0, 0);
}

__device__ __forceinline__ unsigned long long pack_key(float v, int idx) {
    unsigned u = __float_as_uint(v);
    u = (u & 0x80000000u) ? ~u : (u | 0x80000000u);  // monotone float->u32
    return ((unsigned long long)u << 32) | (unsigned)idx;
}

// ---------------------------------------------------------------------
// Kernel 0: zero best[] (argmax accumulator)
// ---------------------------------------------------------------------
__global__ void init_kernel(unsigned long long* __restrict__ best) {
    int i = blockIdx.x * blockDim.x + threadIdx.x;
    if (i < NROWS) best[i] = 0ull;
}

// ---------------------------------------------------------------------
// Kernel 1: per-row L2 norm over concat(a,b); write fp8-e4m3 of
// (x_norm * 64) for the scale-invariant argmax GEMM. fp32 invn kept.
// ---------------------------------------------------------------------
__global__ __launch_bounds__(256) void normalize_kernel(
    const float* __restrict__ a, const float* __restrict__ b,
    unsigned char* __restrict__ xq, float* __restrict__ invn) {
    int wave = threadIdx.x >> 6;
    int lane = threadIdx.x & 63;
    int row  = blockIdx.x * 4 + wave;

    const float* pa = a + (size_t)row * DHALF;
    const float* pb = b + (size_t)row * DHALF;

    float va[6], vb[6];
    float s = 0.0f;
#pragma unroll
    for (int it = 0; it < 6; ++it) { va[it] = pa[lane + 64 * it]; s += va[it] * va[it]; }
#pragma unroll
    for (int it = 0; it < 6; ++it) { vb[it] = pb[lane + 64 * it]; s += vb[it] * vb[it]; }
#pragma unroll
    for (int d = 1; d < 64; d <<= 1) s += __shfl_xor(s, d, 64);

    float inv = 1.0f / fmaxf(sqrtf(s), EPSF);
    if (lane == 0) invn[row] = inv;
    float qs = inv * QSCALE;

    unsigned char* px = xq + (size_t)row * DFULL;
#pragma unroll
    for (int it = 0; it < 6; ++it) {
        __hip_fp8_e4m3 q(va[it] * qs);
        px[lane + 64 * it] = q.__x;
    }
#pragma unroll
    for (int it = 0; it < 6; ++it) {
        __hip_fp8_e4m3 q(vb[it] * qs);
        px[DHALF + lane + 64 * it] = q.__x;
    }
}

// ---------------------------------------------------------------------
// Kernel 2: scaled dots = (64x)·(64x)^T via MX-fp8 K=128 MFMA,
// upper-triangle tile-blocks (symmetry), 128x128 tile, BK=128,
// XOR-swizzled LDS granules. Row+col argmax, diag masked.
// K-loop kept ROLLED (unroll 1): full unroll at 6 trips blew VGPRs to
// 192 -> 2 waves/SIMD -> occupancy collapse (R4). launch_bounds(256,3)
// pins 3 waves/SIMD (<=170 VGPR).
// ---------------------------------------------------------------------
__global__ __launch_bounds__(256, 3) void argmax_kernel(
    const unsigned char* __restrict__ xq,
    unsigned long long* __restrict__ best) {
    __shared__ unsigned char As[128 * 128];
    __shared__ unsigned char Bs[128 * 128];

    // decode upper-triangle pair: k -> (rb <= cb)
    int k = blockIdx.x;
    int i = (int)((sqrtf(8.0f * (float)k + 1.0f) - 1.0f) * 0.5f);
    while ((i + 1) * (i + 2) / 2 <= k) ++i;
    while (i * (i + 1) / 2 > k) --i;
    int cb = i;
    int rb = k - i * (i + 1) / 2;   // rb <= cb
    int r0 = rb * 128, c0 = cb * 128;

    int tid  = threadIdx.x;
    int wave = tid >> 6, lane = tid & 63;
    int wr = wave >> 1, wc = wave & 1;
    int quad = lane >> 4, l15 = lane & 15;

    f32x4 acc[4][4] = {};
    const int SC = 0x7f7f7f7f;      // e8m0 scales = 1.0 in every byte

    // staging source pointers (swizzled granules), hoisted out of K-loop
    const unsigned char* gA[4];
    const unsigned char* gB[4];
    unsigned char* lA[4];
    unsigned char* lB[4];
#pragma unroll
    for (int round = 0; round < 4; ++round) {
        int idx = round * 256 + tid;       // 0..1023
        int r   = idx >> 3;                // 0..127
        int gs  = ((idx & 7) ^ (r & 7)) << 4;
        gA[round] = xq + (size_t)(r0 + r) * DFULL + gs;
        gB[round] = xq + (size_t)(c0 + r) * DFULL + gs;
        lA[round] = &As[idx * 16];
        lB[round] = &Bs[idx * 16];
    }

    // fragment LDS offsets: row = l15 (+tile), k-bytes quad*32..+31
    int s0 = (((quad << 1) ^ (l15 & 7)) << 4);
    int s1 = s0 ^ 16;

#pragma unroll 1
    for (int k0 = 0; k0 < DFULL; k0 += 128) {
#pragma unroll
        for (int round = 0; round < 4; ++round) {
            async_copy16(gA[round] + k0, lA[round]);
            async_copy16(gB[round] + k0, lB[round]);
        }
        __syncthreads();

        union Frag { int4v q[2]; int8v o; };
        Frag bfr[4];
#pragma unroll
        for (int t = 0; t < 4; ++t) {
            const unsigned char* rp = &Bs[(wc * 64 + t * 16 + l15) * 128];
            bfr[t].q[0] = *(const int4v*)(rp + s0);
            bfr[t].q[1] = *(const int4v*)(rp + s1);
        }
#pragma unroll
        for (int ti = 0; ti < 4; ++ti) {
            Frag afr;
            const unsigned char* rp = &As[(wr * 64 + ti * 16 + l15) * 128];
            afr.q[0] = *(const int4v*)(rp + s0);
            afr.q[1] = *(const int4v*)(rp + s1);
#pragma unroll
            for (int tj = 0; tj < 4; ++tj)
                acc[ti][tj] = __builtin_amdgcn_mfma_scale_f32_16x16x128_f8f6f4(
                    afr.o, bfr[tj].o, acc[ti][tj], 0, 0, 0, SC, 0, SC);
        }
        __syncthreads();
    }

    int rbase = r0 + wr * 64, cbase = c0 + wc * 64;

    // Row-direction: best over this block's 128 columns, diag masked.
    // NOTE: scaled dots span ~±4096 — init must be below all finite dots.
#pragma unroll
    for (int ti = 0; ti < 4; ++ti) {
#pragma unroll
        for (int reg = 0; reg < 4; ++reg) {
            int grow = rbase + ti * 16 + quad * 4 + reg;
            float bv = -3.0e38f; int bc = 0;
#pragma unroll
            for (int tj = 0; tj < 4; ++tj) {
                float v   = acc[ti][tj][reg];
                int  gcol = cbase + tj * 16 + l15;
                if (gcol == grow) v = -1.0e30f;   // diagonal mask
                if (v > bv) { bv = v; bc = gcol; }
            }
#pragma unroll
            for (int d = 1; d < 16; d <<= 1) {
                float ov = __shfl_xor(bv, d, 64);
                int   oc = __shfl_xor(bc, d, 64);
                if (ov > bv) { bv = ov; bc = oc; }
            }
            if (l15 == 0) atomicMax(&best[grow], pack_key(bv, bc));
        }
    }

    // Column-direction (off-diagonal blocks): best over this block's 128 rows
    if (rb != cb) {
#pragma unroll
        for (int tj = 0; tj < 4; ++tj) {
            float bv = -3.0e38f; int br = 0;
#pragma unroll
            for (int ti = 0; ti < 4; ++ti)
#pragma unroll
                for (int reg = 0; reg < 4; ++reg) {
                    float v = acc[ti][tj][reg];
                    int grow = rbase + ti * 16 + quad * 4 + reg;
                    if (v > bv) { bv = v; br = grow; }
                }
#pragma unroll
            for (int d = 16; d < 64; d <<= 1) {
                float ov = __shfl_xor(bv, d, 64);
                int   orr = __shfl_xor(br, d, 64);
                if (ov > bv) { bv = ov; br = orr; }
            }
            if (quad == 0) {
                int gcol = cbase + tj * 16 + l15;
                atomicMax(&best[gcol], pack_key(bv, br));
            }
        }
    }
}

// ---------------------------------------------------------------------
// Kernel 3: per-row term = log(||xn_i - xn_j + eps|| + eps), fp32 from
// original inputs. One wave per row. NO atomics — coalesced store.
// ---------------------------------------------------------------------
__global__ __launch_bounds__(256) void loss_kernel(
    const float* __restrict__ a, const float* __restrict__ b,
    const float* __restrict__ invn,
    const unsigned long long* __restrict__ best,
    float* __restrict__ terms) {
    int wave = threadIdx.x >> 6;
    int lane = threadIdx.x & 63;
    int row  = blockIdx.x * 4 + wave;

    int j = (int)(best[row] & 0xffffffffull);
    float ii = invn[row], ij = invn[j];

    const float* pai = a + (size_t)row * DHALF;
    const float* pbi = b + (size_t)row * DHALF;
    const float* paj = a + (size_t)j * DHALF;
    const float* pbj = b + (size_t)j * DHALF;

    float s = 0.0f;
#pragma unroll
    for (int it = 0; it < 6; ++it) {
        int kk = lane + 64 * it;
        float d = pai[kk] * ii - paj[kk] * ij + EPSF;
        s += d * d;
    }
#pragma unroll
    for (int it = 0; it < 6; ++it) {
        int kk = lane + 64 * it;
        float d = pbi[kk] * ii - pbj[kk] * ij + EPSF;
        s += d * d;
    }
#pragma unroll
    for (int d = 1; d < 64; d <<= 1) s += __shfl_xor(s, d, 64);

    if (lane == 0) terms[row] = logf(sqrtf(s) + EPSF);
}

// ---------------------------------------------------------------------
// Kernel 4: single-block tree reduction of terms -> out[0] = -mean
// ---------------------------------------------------------------------
__global__ __launch_bounds__(1024) void reduce_kernel(
    const float* __restrict__ terms, float* __restrict__ out) {
    __shared__ float partial[16];
    int tid = threadIdx.x;
    float s = 0.0f;
#pragma unroll
    for (int it = 0; it < NROWS / 1024; ++it) s += terms[tid + 1024 * it];
#pragma unroll
    for (int d = 1; d < 64; d <<= 1) s += __shfl_xor(s, d, 64);
    if ((tid & 63) == 0) partial[tid >> 6] = s;
    __syncthreads();
    if (tid < 16) {
        s = partial[tid];
#pragma unroll
        for (int d = 1; d < 16; d <<= 1) s += __shfl_xor(s, d, 16);
        if (tid == 0) out[0] = -s * (1.0f / (float)NROWS);
    }
}

// ---------------------------------------------------------------------
extern "C" void kernel_launch(void* const* d_in, const int* in_sizes, int n_in,
                              void* d_out, int out_size, void* d_ws, size_t ws_size,
                              hipStream_t stream) {
    const float* a = (const float*)d_in[0];
    const float* b = (const float*)d_in[1];
    float* out = (float*)d_out;

    char* ws = (char*)d_ws;
    unsigned char* xq = (unsigned char*)ws;                                    // 12582912 B
    unsigned long long* best = (unsigned long long*)(ws + 12582912);           // 131072 B
    float* invn  = (float*)(ws + 12582912 + 131072);                           // 65536 B
    float* terms = (float*)(ws + 12582912 + 131072 + 65536);                   // 65536 B

    const int NTILE = NROWS / 128;                     // 128
    const int NBLK  = NTILE * (NTILE + 1) / 2;         // 8256

    init_kernel<<<NROWS / 256, 256, 0, stream>>>(best);
    normalize_kernel<<<NROWS / 4, 256, 0, stream>>>(a, b, xq, invn);
    argmax_kernel<<<NBLK, 256, 0, stream>>>(xq, best);
    loss_kernel<<<NROWS / 4, 256, 0, stream>>>(a, b, invn, best, terms);
    reduce_kernel<<<1, 1024, 0, stream>>>(terms, out);
}

// Round 6
// 256.636 us; speedup vs baseline: 1.7535x; 1.1210x over previous
//
#include <hip/hip_runtime.h>
#include <hip/hip_bf16.h>
#include <hip/hip_fp8.h>
#include <stdint.h>
#include <math.h>

#define NROWS 16384
#define DHALF 384
#define DFULL 768
#define EPSF  1e-8f
#define QSCALE 64.0f   // power-of-2: lossless rel-err shift into e4m3 normal range

typedef __attribute__((ext_vector_type(4))) float f32x4;
typedef __attribute__((ext_vector_type(4))) int   int4v;
typedef __attribute__((ext_vector_type(8))) int   int8v;

// ---- async global->LDS, 16B per lane (wave-uniform base + lane*16) ----
__device__ __forceinline__ void async_copy16(const void* gptr, void* lptr) {
    __builtin_amdgcn_global_load_lds(
        (const __attribute__((address_space(1))) unsigned int*)gptr,
        (__attribute__((address_space(3))) unsigned int*)lptr,
        16, 0, 0);
}

// monotone float->u32 (order-preserving for all finite floats)
__device__ __forceinline__ unsigned mono_u32(float v) {
    unsigned u = __float_as_uint(v);
    return u ^ ((unsigned)(((int)u) >> 31) | 0x80000000u);
}

// max with a DPP row_ror'd copy (16-lane row, pure VALU — no LDS traffic)
template <int CTRL>
__device__ __forceinline__ unsigned row_max_step(unsigned v) {
    unsigned t = (unsigned)__builtin_amdgcn_update_dpp(
        0, (int)v, CTRL, 0xF, 0xF, false);
    return v > t ? v : t;
}

// ---------------------------------------------------------------------
// Kernel 1: per-row L2 norm over concat(a,b); write fp8-e4m3 of
// (x_norm * 64). Also zeroes best[row] (init fused — ws is re-poisoned
// 0xAA before every launch, and argmax runs after us in stream order).
// ---------------------------------------------------------------------
__global__ __launch_bounds__(256) void normalize_kernel(
    const float* __restrict__ a, const float* __restrict__ b,
    unsigned char* __restrict__ xq, float* __restrict__ invn,
    unsigned long long* __restrict__ best) {
    int wave = threadIdx.x >> 6;
    int lane = threadIdx.x & 63;
    int row  = blockIdx.x * 4 + wave;

    const float* pa = a + (size_t)row * DHALF;
    const float* pb = b + (size_t)row * DHALF;

    float va[6], vb[6];
    float s = 0.0f;
#pragma unroll
    for (int it = 0; it < 6; ++it) { va[it] = pa[lane + 64 * it]; s += va[it] * va[it]; }
#pragma unroll
    for (int it = 0; it < 6; ++it) { vb[it] = pb[lane + 64 * it]; s += vb[it] * vb[it]; }
#pragma unroll
    for (int d = 1; d < 64; d <<= 1) s += __shfl_xor(s, d, 64);

    float inv = 1.0f / fmaxf(sqrtf(s), EPSF);
    if (lane == 0) { invn[row] = inv; best[row] = 0ull; }
    float qs = inv * QSCALE;

    unsigned char* px = xq + (size_t)row * DFULL;
#pragma unroll
    for (int it = 0; it < 6; ++it) {
        __hip_fp8_e4m3 q(va[it] * qs);
        px[lane + 64 * it] = q.__x;
    }
#pragma unroll
    for (int it = 0; it < 6; ++it) {
        __hip_fp8_e4m3 q(vb[it] * qs);
        px[DHALF + lane + 64 * it] = q.__x;
    }
}

// ---------------------------------------------------------------------
// Kernel 2: scaled dots = (64x)·(64x)^T via MX-fp8 K=128 MFMA,
// upper-triangle tile-blocks (symmetry), 128x128 tile, BK=128,
// XOR-swizzled LDS granules. K-loop ROLLED (R4: full unroll -> 192 VGPR
// occupancy collapse). Epilogue: packed-key argmax — index bits folded
// into low 6 bits of the monotone dot key (64-ulp truncation, ~2^-17
// rel, far below fp8 noise; identical truncation row/col keeps
// cross-block atomicMax merges consistent). Row dir reduces via DPP
// row_ror (VALU only); col dir needs 2 shfl_xor per tj (8 DS ops/wave
// vs 144 in R5 — the LDS pipe was ~75% busy, epilogue swizzles ~30%).
// ---------------------------------------------------------------------
__global__ __launch_bounds__(256, 3) void argmax_kernel(
    const unsigned char* __restrict__ xq,
    unsigned long long* __restrict__ best) {
    __shared__ unsigned char As[128 * 128];
    __shared__ unsigned char Bs[128 * 128];

    // decode upper-triangle pair: k -> (rb <= cb)
    int k = blockIdx.x;
    int i = (int)((sqrtf(8.0f * (float)k + 1.0f) - 1.0f) * 0.5f);
    while ((i + 1) * (i + 2) / 2 <= k) ++i;
    while (i * (i + 1) / 2 > k) --i;
    int cb = i;
    int rb = k - i * (i + 1) / 2;   // rb <= cb
    int r0 = rb * 128, c0 = cb * 128;

    int tid  = threadIdx.x;
    int wave = tid >> 6, lane = tid & 63;
    int wr = wave >> 1, wc = wave & 1;
    int quad = lane >> 4, l15 = lane & 15;

    f32x4 acc[4][4] = {};
    const int SC = 0x7f7f7f7f;      // e8m0 scales = 1.0 in every byte

    // staging source/dest pointers (swizzled granules), hoisted
    const unsigned char* gA[4];
    const unsigned char* gB[4];
    unsigned char* lA[4];
    unsigned char* lB[4];
#pragma unroll
    for (int round = 0; round < 4; ++round) {
        int idx = round * 256 + tid;       // 0..1023
        int r   = idx >> 3;                // 0..127
        int gs  = ((idx & 7) ^ (r & 7)) << 4;
        gA[round] = xq + (size_t)(r0 + r) * DFULL + gs;
        gB[round] = xq + (size_t)(c0 + r) * DFULL + gs;
        lA[round] = &As[idx * 16];
        lB[round] = &Bs[idx * 16];
    }

    // fragment LDS offsets: row = l15 (+tile), k-bytes quad*32..+31
    int s0 = (((quad << 1) ^ (l15 & 7)) << 4);
    int s1 = s0 ^ 16;

#pragma unroll 1
    for (int k0 = 0; k0 < DFULL; k0 += 128) {
#pragma unroll
        for (int round = 0; round < 4; ++round) {
            async_copy16(gA[round] + k0, lA[round]);
            async_copy16(gB[round] + k0, lB[round]);
        }
        __syncthreads();

        union Frag { int4v q[2]; int8v o; };
        Frag bfr[4];
#pragma unroll
        for (int t = 0; t < 4; ++t) {
            const unsigned char* rp = &Bs[(wc * 64 + t * 16 + l15) * 128];
            bfr[t].q[0] = *(const int4v*)(rp + s0);
            bfr[t].q[1] = *(const int4v*)(rp + s1);
        }
#pragma unroll
        for (int ti = 0; ti < 4; ++ti) {
            Frag afr;
            const unsigned char* rp = &As[(wr * 64 + ti * 16 + l15) * 128];
            afr.q[0] = *(const int4v*)(rp + s0);
            afr.q[1] = *(const int4v*)(rp + s1);
#pragma unroll
            for (int tj = 0; tj < 4; ++tj)
                acc[ti][tj] = __builtin_amdgcn_mfma_scale_f32_16x16x128_f8f6f4(
                    afr.o, bfr[tj].o, acc[ti][tj], 0, 0, 0, SC, 0, SC);
        }
        __syncthreads();
    }

    int rbase = r0 + wr * 64, cbase = c0 + wc * 64;

    // Row-direction: packed key = mono(v)&~63 | (tj<<4) | l15.
    // Reduce over 16 cols/lane-group with DPP row_ror — zero LDS ops.
#pragma unroll
    for (int ti = 0; ti < 4; ++ti) {
#pragma unroll
        for (int reg = 0; reg < 4; ++reg) {
            int grow = rbase + ti * 16 + quad * 4 + reg;
            unsigned bk = 0;
#pragma unroll
            for (int tj = 0; tj < 4; ++tj) {
                float v   = acc[ti][tj][reg];
                int  gcol = cbase + tj * 16 + l15;
                if (gcol == grow) v = -1.0e30f;   // diagonal mask
                unsigned u = (mono_u32(v) & ~63u) | (unsigned)((tj << 4) | l15);
                bk = bk > u ? bk : u;
            }
            bk = row_max_step<0x121>(bk);   // ror 1
            bk = row_max_step<0x122>(bk);   // ror 2
            bk = row_max_step<0x124>(bk);   // ror 4
            bk = row_max_step<0x128>(bk);   // ror 8
            if (l15 == 0) {
                int col = cbase + (int)(((bk >> 4) & 3u) * 16u + (bk & 15u));
                unsigned long long gk =
                    ((unsigned long long)(bk & ~63u) << 32) | (unsigned)col;
                atomicMax(&best[grow], gk);
            }
        }
    }

    // Column-direction (off-diagonal blocks): packed key low bits =
    // (ti<<4)|(quad<<2)|reg; lane-local fold then xor-16/32 shuffles.
    if (rb != cb) {
#pragma unroll
        for (int tj = 0; tj < 4; ++tj) {
            unsigned bk = 0;
#pragma unroll
            for (int ti = 0; ti < 4; ++ti)
#pragma unroll
                for (int reg = 0; reg < 4; ++reg) {
                    unsigned u = (mono_u32(acc[ti][tj][reg]) & ~63u) |
                                 (unsigned)((ti << 4) | (quad << 2) | reg);
                    bk = bk > u ? bk : u;
                }
            unsigned t16 = (unsigned)__shfl_xor((int)bk, 16, 64);
            bk = bk > t16 ? bk : t16;
            unsigned t32 = (unsigned)__shfl_xor((int)bk, 32, 64);
            bk = bk > t32 ? bk : t32;
            if (quad == 0) {
                int grow = rbase + (int)(((bk >> 4) & 3u) * 16u +
                                         ((bk >> 2) & 3u) * 4u + (bk & 3u));
                int gcol = cbase + tj * 16 + l15;
                unsigned long long gk =
                    ((unsigned long long)(bk & ~63u) << 32) | (unsigned)grow;
                atomicMax(&best[gcol], gk);
            }
        }
    }
}

// ---------------------------------------------------------------------
// Kernel 3: per-row term = log(||xn_i - xn_j + eps|| + eps), fp32 from
// original inputs. One wave per row. NO atomics — coalesced store.
// ---------------------------------------------------------------------
__global__ __launch_bounds__(256) void loss_kernel(
    const float* __restrict__ a, const float* __restrict__ b,
    const float* __restrict__ invn,
    const unsigned long long* __restrict__ best,
    float* __restrict__ terms) {
    int wave = threadIdx.x >> 6;
    int lane = threadIdx.x & 63;
    int row  = blockIdx.x * 4 + wave;

    int j = (int)(best[row] & 0xffffffffull);
    float ii = invn[row], ij = invn[j];

    const float* pai = a + (size_t)row * DHALF;
    const float* pbi = b + (size_t)row * DHALF;
    const float* paj = a + (size_t)j * DHALF;
    const float* pbj = b + (size_t)j * DHALF;

    float s = 0.0f;
#pragma unroll
    for (int it = 0; it < 6; ++it) {
        int kk = lane + 64 * it;
        float d = pai[kk] * ii - paj[kk] * ij + EPSF;
        s += d * d;
    }
#pragma unroll
    for (int it = 0; it < 6; ++it) {
        int kk = lane + 64 * it;
        float d = pbi[kk] * ii - pbj[kk] * ij + EPSF;
        s += d * d;
    }
#pragma unroll
    for (int d = 1; d < 64; d <<= 1) s += __shfl_xor(s, d, 64);

    if (lane == 0) terms[row] = logf(sqrtf(s) + EPSF);
}

// ---------------------------------------------------------------------
// Kernel 4: single-block tree reduction of terms -> out[0] = -mean
// (writes out unconditionally every call — no init needed)
// ---------------------------------------------------------------------
__global__ __launch_bounds__(1024) void reduce_kernel(
    const float* __restrict__ terms, float* __restrict__ out) {
    __shared__ float partial[16];
    int tid = threadIdx.x;
    float s = 0.0f;
#pragma unroll
    for (int it = 0; it < NROWS / 1024; ++it) s += terms[tid + 1024 * it];
#pragma unroll
    for (int d = 1; d < 64; d <<= 1) s += __shfl_xor(s, d, 64);
    if ((tid & 63) == 0) partial[tid >> 6] = s;
    __syncthreads();
    if (tid < 16) {
        s = partial[tid];
#pragma unroll
        for (int d = 1; d < 16; d <<= 1) s += __shfl_xor(s, d, 16);
        if (tid == 0) out[0] = -s * (1.0f / (float)NROWS);
    }
}

// ---------------------------------------------------------------------
extern "C" void kernel_launch(void* const* d_in, const int* in_sizes, int n_in,
                              void* d_out, int out_size, void* d_ws, size_t ws_size,
                              hipStream_t stream) {
    const float* a = (const float*)d_in[0];
    const float* b = (const float*)d_in[1];
    float* out = (float*)d_out;

    char* ws = (char*)d_ws;
    unsigned char* xq = (unsigned char*)ws;                                    // 12582912 B
    unsigned long long* best = (unsigned long long*)(ws + 12582912);           // 131072 B
    float* invn  = (float*)(ws + 12582912 + 131072);                           // 65536 B
    float* terms = (float*)(ws + 12582912 + 131072 + 65536);                   // 65536 B

    const int NTILE = NROWS / 128;                     // 128
    const int NBLK  = NTILE * (NTILE + 1) / 2;         // 8256

    normalize_kernel<<<NROWS / 4, 256, 0, stream>>>(a, b, xq, invn, best);
    argmax_kernel<<<NBLK, 256, 0, stream>>>(xq, best);
    loss_kernel<<<NROWS / 4, 256, 0, stream>>>(a, b, invn, best, terms);
    reduce_kernel<<<1, 1024, 0, stream>>>(terms, out);
}

// Round 7
// 211.789 us; speedup vs baseline: 2.1249x; 1.2118x over previous
//
#include <hip/hip_runtime.h>
#include <hip/hip_bf16.h>
#include <stdint.h>
#include <math.h>

#define NROWS 16384
#define DHALF 384
#define DFULL 768
#define ROWB  384      // bytes per fp4 row: 768 elems * 4 bit
#define EPSF  1e-8f
#define QSCALE 64.0f   // N(0,0.036)*64 -> N(0,2.3): centered in e2m1 range +-6

typedef __attribute__((ext_vector_type(4))) float f32x4;
typedef __attribute__((ext_vector_type(4))) int   int4v;
typedef __attribute__((ext_vector_type(8))) int   int8v;

// ---- async global->LDS, 16B per lane (wave-uniform base + lane*16) ----
__device__ __forceinline__ void async_copy16(const void* gptr, void* lptr) {
    __builtin_amdgcn_global_load_lds(
        (const __attribute__((address_space(1))) unsigned int*)gptr,
        (__attribute__((address_space(3))) unsigned int*)lptr,
        16, 0, 0);
}

// monotone float->u32 (order-preserving for all finite floats)
__device__ __forceinline__ unsigned mono_u32(float v) {
    unsigned u = __float_as_uint(v);
    return u ^ ((unsigned)(((int)u) >> 31) | 0x80000000u);
}

// max with a DPP row_ror'd copy (16-lane row, pure VALU — no LDS traffic)
template <int CTRL>
__device__ __forceinline__ unsigned row_max_step(unsigned v) {
    unsigned t = (unsigned)__builtin_amdgcn_update_dpp(
        0, (int)v, CTRL, 0xF, 0xF, false);
    return v > t ? v : t;
}

// fp4 e2m1 encode, round-to-nearest: values {0,.5,1,1.5,2,3,4,6} (+sign)
__device__ __forceinline__ unsigned enc_fp4(float v) {
    float a = fabsf(v);
    unsigned c = (unsigned)(a >= 0.25f) + (a >= 0.75f) + (a >= 1.25f) +
                 (a >= 1.75f) + (a >= 2.5f) + (a >= 3.5f) + (a >= 5.0f);
    return c | (v < 0.0f ? 8u : 0u);
}

// pad 4-dword fp4 operand to the v8i32 the builtin wants (HW reads v[0:3])
__device__ __forceinline__ int8v to8(int4v q) {
    int8v r;
    r[0] = q[0]; r[1] = q[1]; r[2] = q[2]; r[3] = q[3];
    r[4] = 0; r[5] = 0; r[6] = 0; r[7] = 0;
    return r;
}

// ---------------------------------------------------------------------
// Kernel 1: per-row L2 norm over concat(a,b); write fp4-e2m1 nibbles of
// (x_norm * 64), pair-packed (elem 2p low nibble, 2p+1 high). float2
// loads so each lane owns contiguous element pairs. Zeroes best[row].
// ---------------------------------------------------------------------
__global__ __launch_bounds__(256) void normalize_kernel(
    const float* __restrict__ a, const float* __restrict__ b,
    unsigned char* __restrict__ xq, float* __restrict__ invn,
    unsigned long long* __restrict__ best) {
    int wave = threadIdx.x >> 6;
    int lane = threadIdx.x & 63;
    int row  = blockIdx.x * 4 + wave;

    const float2* pa = (const float2*)(a + (size_t)row * DHALF);  // 192 pairs
    const float2* pb = (const float2*)(b + (size_t)row * DHALF);

    float2 va[3], vb[3];
    float s = 0.0f;
#pragma unroll
    for (int it = 0; it < 3; ++it) {
        va[it] = pa[lane + 64 * it];
        s += va[it].x * va[it].x + va[it].y * va[it].y;
    }
#pragma unroll
    for (int it = 0; it < 3; ++it) {
        vb[it] = pb[lane + 64 * it];
        s += vb[it].x * vb[it].x + vb[it].y * vb[it].y;
    }
#pragma unroll
    for (int d = 1; d < 64; d <<= 1) s += __shfl_xor(s, d, 64);

    float inv = 1.0f / fmaxf(sqrtf(s), EPSF);
    if (lane == 0) { invn[row] = inv; best[row] = 0ull; }
    float qs = inv * QSCALE;

    unsigned char* px = xq + (size_t)row * ROWB;
#pragma unroll
    for (int it = 0; it < 3; ++it)
        px[lane + 64 * it] =
            (unsigned char)(enc_fp4(va[it].x * qs) | (enc_fp4(va[it].y * qs) << 4));
#pragma unroll
    for (int it = 0; it < 3; ++it)
        px[192 + lane + 64 * it] =
            (unsigned char)(enc_fp4(vb[it].x * qs) | (enc_fp4(vb[it].y * qs) << 4));
}

// ---------------------------------------------------------------------
// Kernel 2: scaled dots via MX-fp4 K=128 MFMA (fmt code 4), 128x128
// tile, BK=128 elems = 64 B/row, upper-triangle blocks. LDS halves to
// 16 KB; one ds_read_b128 per fragment. Swizzle slot = g ^ ((r^(r>>2))&3)
// keeps staging AND frag reads at 2-way (free). K-loop ROLLED (R4
// lesson). Packed-key DPP argmax epilogue (R6). Distances recomputed in
// fp32 later, so fp4 only risks near-tie neighbor flips (~1e-3 bias).
// ---------------------------------------------------------------------
__global__ __launch_bounds__(256, 3) void argmax_kernel(
    const unsigned char* __restrict__ xq,
    unsigned long long* __restrict__ best) {
    __shared__ unsigned char As[128 * 64];
    __shared__ unsigned char Bs[128 * 64];

    // decode upper-triangle pair: k -> (rb <= cb)
    int k = blockIdx.x;
    int i = (int)((sqrtf(8.0f * (float)k + 1.0f) - 1.0f) * 0.5f);
    while ((i + 1) * (i + 2) / 2 <= k) ++i;
    while (i * (i + 1) / 2 > k) --i;
    int cb = i;
    int rb = k - i * (i + 1) / 2;   // rb <= cb
    int r0 = rb * 128, c0 = cb * 128;

    int tid  = threadIdx.x;
    int wave = tid >> 6, lane = tid & 63;
    int wr = wave >> 1, wc = wave & 1;
    int quad = lane >> 4, l15 = lane & 15;

    f32x4 acc[4][4] = {};
    const int SC = 0x7f7f7f7f;      // e8m0 scales = 1.0 in every byte

    // staging pointers: 2 rounds x 256 threads cover 512 granules/tile
    const unsigned char* gA[2];
    const unsigned char* gB[2];
    unsigned char* lA[2];
    unsigned char* lB[2];
#pragma unroll
    for (int r2 = 0; r2 < 2; ++r2) {
        int idx = r2 * 256 + tid;          // 0..511
        int r   = idx >> 2;                // 0..127
        int s   = idx & 3;                 // dst slot
        int g   = s ^ ((r ^ (r >> 2)) & 3);   // swizzled source granule
        gA[r2] = xq + (size_t)(r0 + r) * ROWB + (g << 4);
        gB[r2] = xq + (size_t)(c0 + r) * ROWB + (g << 4);
        lA[r2] = &As[idx * 16];
        lB[r2] = &Bs[idx * 16];
    }

    // fragment LDS offset: lane's 32 k-elems = source granule `quad`
    int s0 = ((quad ^ ((l15 ^ (l15 >> 2)) & 3)) << 4);

#pragma unroll 1
    for (int k0b = 0; k0b < ROWB; k0b += 64) {   // 6 K-steps of 128 elems
        async_copy16(gA[0] + k0b, lA[0]);
        async_copy16(gA[1] + k0b, lA[1]);
        async_copy16(gB[0] + k0b, lB[0]);
        async_copy16(gB[1] + k0b, lB[1]);
        __syncthreads();

        int4v bq[4];
#pragma unroll
        for (int t = 0; t < 4; ++t)
            bq[t] = *(const int4v*)(&Bs[(wc * 64 + t * 16 + l15) * 64] + s0);
#pragma unroll
        for (int ti = 0; ti < 4; ++ti) {
            int4v aq = *(const int4v*)(&As[(wr * 64 + ti * 16 + l15) * 64] + s0);
            int8v a8 = to8(aq);
#pragma unroll
            for (int tj = 0; tj < 4; ++tj)
                acc[ti][tj] = __builtin_amdgcn_mfma_scale_f32_16x16x128_f8f6f4(
                    a8, to8(bq[tj]), acc[ti][tj], 4, 4, 0, SC, 0, SC);
        }
        __syncthreads();
    }

    int rbase = r0 + wr * 64, cbase = c0 + wc * 64;

    // Row-direction: packed key = mono(v)&~63 | (tj<<4) | l15; DPP reduce.
#pragma unroll
    for (int ti = 0; ti < 4; ++ti) {
#pragma unroll
        for (int reg = 0; reg < 4; ++reg) {
            int grow = rbase + ti * 16 + quad * 4 + reg;
            unsigned bk = 0;
#pragma unroll
            for (int tj = 0; tj < 4; ++tj) {
                float v   = acc[ti][tj][reg];
                int  gcol = cbase + tj * 16 + l15;
                if (gcol == grow) v = -1.0e30f;   // diagonal mask
                unsigned u = (mono_u32(v) & ~63u) | (unsigned)((tj << 4) | l15);
                bk = bk > u ? bk : u;
            }
            bk = row_max_step<0x121>(bk);   // ror 1
            bk = row_max_step<0x122>(bk);   // ror 2
            bk = row_max_step<0x124>(bk);   // ror 4
            bk = row_max_step<0x128>(bk);   // ror 8
            if (l15 == 0) {
                int col = cbase + (int)(((bk >> 4) & 3u) * 16u + (bk & 15u));
                unsigned long long gk =
                    ((unsigned long long)(bk & ~63u) << 32) | (unsigned)col;
                atomicMax(&best[grow], gk);
            }
        }
    }

    // Column-direction (off-diagonal blocks)
    if (rb != cb) {
#pragma unroll
        for (int tj = 0; tj < 4; ++tj) {
            unsigned bk = 0;
#pragma unroll
            for (int ti = 0; ti < 4; ++ti)
#pragma unroll
                for (int reg = 0; reg < 4; ++reg) {
                    unsigned u = (mono_u32(acc[ti][tj][reg]) & ~63u) |
                                 (unsigned)((ti << 4) | (quad << 2) | reg);
                    bk = bk > u ? bk : u;
                }
            unsigned t16 = (unsigned)__shfl_xor((int)bk, 16, 64);
            bk = bk > t16 ? bk : t16;
            unsigned t32 = (unsigned)__shfl_xor((int)bk, 32, 64);
            bk = bk > t32 ? bk : t32;
            if (quad == 0) {
                int grow = rbase + (int)(((bk >> 4) & 3u) * 16u +
                                         ((bk >> 2) & 3u) * 4u + (bk & 3u));
                int gcol = cbase + tj * 16 + l15;
                unsigned long long gk =
                    ((unsigned long long)(bk & ~63u) << 32) | (unsigned)grow;
                atomicMax(&best[gcol], gk);
            }
        }
    }
}

// ---------------------------------------------------------------------
// Kernel 3: per-row term = log(||xn_i - xn_j + eps|| + eps), fp32 from
// original inputs (float2 loads). One wave per row, coalesced store.
// ---------------------------------------------------------------------
__global__ __launch_bounds__(256) void loss_kernel(
    const float* __restrict__ a, const float* __restrict__ b,
    const float* __restrict__ invn,
    const unsigned long long* __restrict__ best,
    float* __restrict__ terms) {
    int wave = threadIdx.x >> 6;
    int lane = threadIdx.x & 63;
    int row  = blockIdx.x * 4 + wave;

    int j = (int)(best[row] & 0xffffffffull);
    float ii = invn[row], ij = invn[j];

    const float2* pai = (const float2*)(a + (size_t)row * DHALF);
    const float2* pbi = (const float2*)(b + (size_t)row * DHALF);
    const float2* paj = (const float2*)(a + (size_t)j * DHALF);
    const float2* pbj = (const float2*)(b + (size_t)j * DHALF);

    float s = 0.0f;
#pragma unroll
    for (int it = 0; it < 3; ++it) {
        int kk = lane + 64 * it;
        float2 di = pai[kk], dj = paj[kk];
        float dx = di.x * ii - dj.x * ij + EPSF;
        float dy = di.y * ii - dj.y * ij + EPSF;
        s += dx * dx + dy * dy;
    }
#pragma unroll
    for (int it = 0; it < 3; ++it) {
        int kk = lane + 64 * it;
        float2 di = pbi[kk], dj = pbj[kk];
        float dx = di.x * ii - dj.x * ij + EPSF;
        float dy = di.y * ii - dj.y * ij + EPSF;
        s += dx * dx + dy * dy;
    }
#pragma unroll
    for (int d = 1; d < 64; d <<= 1) s += __shfl_xor(s, d, 64);

    if (lane == 0) terms[row] = logf(sqrtf(s) + EPSF);
}

// ---------------------------------------------------------------------
// Kernel 4: single-block tree reduction of terms -> out[0] = -mean
// ---------------------------------------------------------------------
__global__ __launch_bounds__(1024) void reduce_kernel(
    const float* __restrict__ terms, float* __restrict__ out) {
    __shared__ float partial[16];
    int tid = threadIdx.x;
    float s = 0.0f;
#pragma unroll
    for (int it = 0; it < NROWS / 1024; ++it) s += terms[tid + 1024 * it];
#pragma unroll
    for (int d = 1; d < 64; d <<= 1) s += __shfl_xor(s, d, 64);
    if ((tid & 63) == 0) partial[tid >> 6] = s;
    __syncthreads();
    if (tid < 16) {
        s = partial[tid];
#pragma unroll
        for (int d = 1; d < 16; d <<= 1) s += __shfl_xor(s, d, 16);
        if (tid == 0) out[0] = -s * (1.0f / (float)NROWS);
    }
}

// ---------------------------------------------------------------------
extern "C" void kernel_launch(void* const* d_in, const int* in_sizes, int n_in,
                              void* d_out, int out_size, void* d_ws, size_t ws_size,
                              hipStream_t stream) {
    const float* a = (const float*)d_in[0];
    const float* b = (const float*)d_in[1];
    float* out = (float*)d_out;

    char* ws = (char*)d_ws;
    unsigned char* xq = (unsigned char*)ws;                                    // 6291456 B
    unsigned long long* best = (unsigned long long*)(ws + 6291456);            // 131072 B
    float* invn  = (float*)(ws + 6291456 + 131072);                            // 65536 B
    float* terms = (float*)(ws + 6291456 + 131072 + 65536);                    // 65536 B

    const int NTILE = NROWS / 128;                     // 128
    const int NBLK  = NTILE * (NTILE + 1) / 2;         // 8256

    normalize_kernel<<<NROWS / 4, 256, 0, stream>>>(a, b, xq, invn, best);
    argmax_kernel<<<NBLK, 256, 0, stream>>>(xq, best);
    loss_kernel<<<NROWS / 4, 256, 0, stream>>>(a, b, invn, best, terms);
    reduce_kernel<<<1, 1024, 0, stream>>>(terms, out);
}

// Round 8
// 209.705 us; speedup vs baseline: 2.1460x; 1.0099x over previous
//
#include <hip/hip_runtime.h>
#include <hip/hip_bf16.h>
#include <stdint.h>
#include <math.h>

#define NROWS 16384
#define DHALF 384
#define DFULL 768
#define ROWB  384      // bytes per fp4 row: 768 elems * 4 bit
#define EPSF  1e-8f
#define QSCALE 64.0f   // N(0,0.036)*64 -> N(0,2.3): centered in e2m1 range +-6

typedef __attribute__((ext_vector_type(4))) float f32x4;
typedef __attribute__((ext_vector_type(4))) int   int4v;
typedef __attribute__((ext_vector_type(8))) int   int8v;

// ---- async global->LDS, 16B per lane (wave-uniform base + lane*16) ----
__device__ __forceinline__ void async_copy16(const void* gptr, void* lptr) {
    __builtin_amdgcn_global_load_lds(
        (const __attribute__((address_space(1))) unsigned int*)gptr,
        (__attribute__((address_space(3))) unsigned int*)lptr,
        16, 0, 0);
}

// monotone float->u32 (order-preserving for all finite floats)
__device__ __forceinline__ unsigned mono_u32(float v) {
    unsigned u = __float_as_uint(v);
    return u ^ ((unsigned)(((int)u) >> 31) | 0x80000000u);
}

// max with a DPP row_ror'd copy (16-lane row, pure VALU — no LDS traffic)
template <int CTRL>
__device__ __forceinline__ unsigned row_max_step(unsigned v) {
    unsigned t = (unsigned)__builtin_amdgcn_update_dpp(
        0, (int)v, CTRL, 0xF, 0xF, false);
    return v > t ? v : t;
}

// fp4 e2m1 encode, round-to-nearest: values {0,.5,1,1.5,2,3,4,6} (+sign)
__device__ __forceinline__ unsigned enc_fp4(float v) {
    float a = fabsf(v);
    unsigned c = (unsigned)(a >= 0.25f) + (a >= 0.75f) + (a >= 1.25f) +
                 (a >= 1.75f) + (a >= 2.5f) + (a >= 3.5f) + (a >= 5.0f);
    return c | (v < 0.0f ? 8u : 0u);
}

// pad 4-dword fp4 operand to the v8i32 the builtin wants (HW reads v[0:3])
__device__ __forceinline__ int8v to8(int4v q) {
    int8v r;
    r[0] = q[0]; r[1] = q[1]; r[2] = q[2]; r[3] = q[3];
    r[4] = 0; r[5] = 0; r[6] = 0; r[7] = 0;
    return r;
}

// ---------------------------------------------------------------------
// Kernel 1: per-row L2 norm over concat(a,b); write fp4-e2m1 nibbles of
// (x_norm * 64), pair-packed. Zeroes best[row].
// ---------------------------------------------------------------------
__global__ __launch_bounds__(256) void normalize_kernel(
    const float* __restrict__ a, const float* __restrict__ b,
    unsigned char* __restrict__ xq, float* __restrict__ invn,
    unsigned long long* __restrict__ best) {
    int wave = threadIdx.x >> 6;
    int lane = threadIdx.x & 63;
    int row  = blockIdx.x * 4 + wave;

    const float2* pa = (const float2*)(a + (size_t)row * DHALF);  // 192 pairs
    const float2* pb = (const float2*)(b + (size_t)row * DHALF);

    float2 va[3], vb[3];
    float s = 0.0f;
#pragma unroll
    for (int it = 0; it < 3; ++it) {
        va[it] = pa[lane + 64 * it];
        s += va[it].x * va[it].x + va[it].y * va[it].y;
    }
#pragma unroll
    for (int it = 0; it < 3; ++it) {
        vb[it] = pb[lane + 64 * it];
        s += vb[it].x * vb[it].x + vb[it].y * vb[it].y;
    }
#pragma unroll
    for (int d = 1; d < 64; d <<= 1) s += __shfl_xor(s, d, 64);

    float inv = 1.0f / fmaxf(sqrtf(s), EPSF);
    if (lane == 0) { invn[row] = inv; best[row] = 0ull; }
    float qs = inv * QSCALE;

    unsigned char* px = xq + (size_t)row * ROWB;
#pragma unroll
    for (int it = 0; it < 3; ++it)
        px[lane + 64 * it] =
            (unsigned char)(enc_fp4(va[it].x * qs) | (enc_fp4(va[it].y * qs) << 4));
#pragma unroll
    for (int it = 0; it < 3; ++it)
        px[192 + lane + 64 * it] =
            (unsigned char)(enc_fp4(vb[it].x * qs) | (enc_fp4(vb[it].y * qs) << 4));
}

// ---------------------------------------------------------------------
// Kernel 2: scaled dots via MX-fp4 K=128 MFMA, 128x128 tile, BK=128
// elems = 64 B/row, upper-triangle blocks (symmetry). DOUBLE-BUFFERED
// LDS with stage-ahead: tile k+1's global_load_lds issue BEFORE
// compute(k), so the compiler's s_waitcnt vmcnt(0) at the single
// per-iteration barrier drains loads that已 had the whole compute phase
// (~500+ cyc) in flight. Barriers: 12 -> 6 per block. (R7 ledger: no
// pipe >49% busy -> ~50% stall cycles, dominated by per-K-step exposed
// staging latency.) K-loop ROLLED (R4: unroll -> VGPR collapse).
// Packed-key DPP argmax epilogue (R6). 2-way-max LDS swizzle (R7).
// ---------------------------------------------------------------------
__global__ __launch_bounds__(256, 3) void argmax_kernel(
    const unsigned char* __restrict__ xq,
    unsigned long long* __restrict__ best) {
    __shared__ unsigned char As[2][128 * 64];
    __shared__ unsigned char Bs[2][128 * 64];

    // decode upper-triangle pair: k -> (rb <= cb)
    int k = blockIdx.x;
    int i = (int)((sqrtf(8.0f * (float)k + 1.0f) - 1.0f) * 0.5f);
    while ((i + 1) * (i + 2) / 2 <= k) ++i;
    while (i * (i + 1) / 2 > k) --i;
    int cb = i;
    int rb = k - i * (i + 1) / 2;   // rb <= cb
    int r0 = rb * 128, c0 = cb * 128;

    int tid  = threadIdx.x;
    int wave = tid >> 6, lane = tid & 63;
    int wr = wave >> 1, wc = wave & 1;
    int quad = lane >> 4, l15 = lane & 15;

    f32x4 acc[4][4] = {};
    const int SC = 0x7f7f7f7f;      // e8m0 scales = 1.0 in every byte

    // staging pointers: 2 rounds x 256 threads cover 512 granules/tile
    const unsigned char* gA[2];
    const unsigned char* gB[2];
    int lofs[2];
#pragma unroll
    for (int r2 = 0; r2 < 2; ++r2) {
        int idx = r2 * 256 + tid;          // 0..511
        int r   = idx >> 2;                // 0..127
        int s   = idx & 3;                 // dst slot
        int g   = s ^ ((r ^ (r >> 2)) & 3);   // swizzled source granule
        gA[r2] = xq + (size_t)(r0 + r) * ROWB + (g << 4);
        gB[r2] = xq + (size_t)(c0 + r) * ROWB + (g << 4);
        lofs[r2] = idx * 16;
    }

    // fragment LDS offset: lane's 32 k-elems = source granule `quad`
    int s0 = ((quad ^ ((l15 ^ (l15 >> 2)) & 3)) << 4);

    auto stage = [&](int k0b, int buf) {
        async_copy16(gA[0] + k0b, &As[buf][lofs[0]]);
        async_copy16(gA[1] + k0b, &As[buf][lofs[1]]);
        async_copy16(gB[0] + k0b, &Bs[buf][lofs[0]]);
        async_copy16(gB[1] + k0b, &Bs[buf][lofs[1]]);
    };
    auto compute = [&](int buf) {
        int4v bq[4];
#pragma unroll
        for (int t = 0; t < 4; ++t)
            bq[t] = *(const int4v*)(&Bs[buf][(wc * 64 + t * 16 + l15) * 64 + s0]);
#pragma unroll
        for (int ti = 0; ti < 4; ++ti) {
            int4v aq = *(const int4v*)(&As[buf][(wr * 64 + ti * 16 + l15) * 64 + s0]);
            int8v a8 = to8(aq);
#pragma unroll
            for (int tj = 0; tj < 4; ++tj)
                acc[ti][tj] = __builtin_amdgcn_mfma_scale_f32_16x16x128_f8f6f4(
                    a8, to8(bq[tj]), acc[ti][tj], 4, 4, 0, SC, 0, SC);
        }
    };

    stage(0, 0);
    __syncthreads();
    int buf = 0;
#pragma unroll 1
    for (int k0b = 64; k0b < ROWB; k0b += 64) {   // 5 pipelined steps
        stage(k0b, buf ^ 1);     // in flight during compute(buf)
        compute(buf);
        __syncthreads();         // drains stage(buf^1); releases buf for k+2
        buf ^= 1;
    }
    compute(buf);                // last tile; epilogue is register-only

    int rbase = r0 + wr * 64, cbase = c0 + wc * 64;

    // Row-direction: packed key = mono(v)&~63 | (tj<<4) | l15; DPP reduce.
#pragma unroll
    for (int ti = 0; ti < 4; ++ti) {
#pragma unroll
        for (int reg = 0; reg < 4; ++reg) {
            int grow = rbase + ti * 16 + quad * 4 + reg;
            unsigned bk = 0;
#pragma unroll
            for (int tj = 0; tj < 4; ++tj) {
                float v   = acc[ti][tj][reg];
                int  gcol = cbase + tj * 16 + l15;
                if (gcol == grow) v = -1.0e30f;   // diagonal mask
                unsigned u = (mono_u32(v) & ~63u) | (unsigned)((tj << 4) | l15);
                bk = bk > u ? bk : u;
            }
            bk = row_max_step<0x121>(bk);   // ror 1
            bk = row_max_step<0x122>(bk);   // ror 2
            bk = row_max_step<0x124>(bk);   // ror 4
            bk = row_max_step<0x128>(bk);   // ror 8
            if (l15 == 0) {
                int col = cbase + (int)(((bk >> 4) & 3u) * 16u + (bk & 15u));
                unsigned long long gk =
                    ((unsigned long long)(bk & ~63u) << 32) | (unsigned)col;
                atomicMax(&best[grow], gk);
            }
        }
    }

    // Column-direction (off-diagonal blocks)
    if (rb != cb) {
#pragma unroll
        for (int tj = 0; tj < 4; ++tj) {
            unsigned bk = 0;
#pragma unroll
            for (int ti = 0; ti < 4; ++ti)
#pragma unroll
                for (int reg = 0; reg < 4; ++reg) {
                    unsigned u = (mono_u32(acc[ti][tj][reg]) & ~63u) |
                                 (unsigned)((ti << 4) | (quad << 2) | reg);
                    bk = bk > u ? bk : u;
                }
            unsigned t16 = (unsigned)__shfl_xor((int)bk, 16, 64);
            bk = bk > t16 ? bk : t16;
            unsigned t32 = (unsigned)__shfl_xor((int)bk, 32, 64);
            bk = bk > t32 ? bk : t32;
            if (quad == 0) {
                int grow = rbase + (int)(((bk >> 4) & 3u) * 16u +
                                         ((bk >> 2) & 3u) * 4u + (bk & 3u));
                int gcol = cbase + tj * 16 + l15;
                unsigned long long gk =
                    ((unsigned long long)(bk & ~63u) << 32) | (unsigned)grow;
                atomicMax(&best[gcol], gk);
            }
        }
    }
}

// ---------------------------------------------------------------------
// Kernel 3: per-row term = log(||xn_i - xn_j + eps|| + eps), fp32 from
// original inputs (float2 loads). One wave per row, coalesced store.
// ---------------------------------------------------------------------
__global__ __launch_bounds__(256) void loss_kernel(
    const float* __restrict__ a, const float* __restrict__ b,
    const float* __restrict__ invn,
    const unsigned long long* __restrict__ best,
    float* __restrict__ terms) {
    int wave = threadIdx.x >> 6;
    int lane = threadIdx.x & 63;
    int row  = blockIdx.x * 4 + wave;

    int j = (int)(best[row] & 0xffffffffull);
    float ii = invn[row], ij = invn[j];

    const float2* pai = (const float2*)(a + (size_t)row * DHALF);
    const float2* pbi = (const float2*)(b + (size_t)row * DHALF);
    const float2* paj = (const float2*)(a + (size_t)j * DHALF);
    const float2* pbj = (const float2*)(b + (size_t)j * DHALF);

    float s = 0.0f;
#pragma unroll
    for (int it = 0; it < 3; ++it) {
        int kk = lane + 64 * it;
        float2 di = pai[kk], dj = paj[kk];
        float dx = di.x * ii - dj.x * ij + EPSF;
        float dy = di.y * ii - dj.y * ij + EPSF;
        s += dx * dx + dy * dy;
    }
#pragma unroll
    for (int it = 0; it < 3; ++it) {
        int kk = lane + 64 * it;
        float2 di = pbi[kk], dj = pbj[kk];
        float dx = di.x * ii - dj.x * ij + EPSF;
        float dy = di.y * ii - dj.y * ij + EPSF;
        s += dx * dx + dy * dy;
    }
#pragma unroll
    for (int d = 1; d < 64; d <<= 1) s += __shfl_xor(s, d, 64);

    if (lane == 0) terms[row] = logf(sqrtf(s) + EPSF);
}

// ---------------------------------------------------------------------
// Kernel 4: single-block tree reduction of terms -> out[0] = -mean
// ---------------------------------------------------------------------
__global__ __launch_bounds__(1024) void reduce_kernel(
    const float* __restrict__ terms, float* __restrict__ out) {
    __shared__ float partial[16];
    int tid = threadIdx.x;
    float s = 0.0f;
#pragma unroll
    for (int it = 0; it < NROWS / 1024; ++it) s += terms[tid + 1024 * it];
#pragma unroll
    for (int d = 1; d < 64; d <<= 1) s += __shfl_xor(s, d, 64);
    if ((tid & 63) == 0) partial[tid >> 6] = s;
    __syncthreads();
    if (tid < 16) {
        s = partial[tid];
#pragma unroll
        for (int d = 1; d < 16; d <<= 1) s += __shfl_xor(s, d, 16);
        if (tid == 0) out[0] = -s * (1.0f / (float)NROWS);
    }
}

// ---------------------------------------------------------------------
extern "C" void kernel_launch(void* const* d_in, const int* in_sizes, int n_in,
                              void* d_out, int out_size, void* d_ws, size_t ws_size,
                              hipStream_t stream) {
    const float* a = (const float*)d_in[0];
    const float* b = (const float*)d_in[1];
    float* out = (float*)d_out;

    char* ws = (char*)d_ws;
    unsigned char* xq = (unsigned char*)ws;                                    // 6291456 B
    unsigned long long* best = (unsigned long long*)(ws + 6291456);            // 131072 B
    float* invn  = (float*)(ws + 6291456 + 131072);                            // 65536 B
    float* terms = (float*)(ws + 6291456 + 131072 + 65536);                    // 65536 B

    const int NTILE = NROWS / 128;                     // 128
    const int NBLK  = NTILE * (NTILE + 1) / 2;         // 8256

    normalize_kernel<<<NROWS / 4, 256, 0, stream>>>(a, b, xq, invn, best);
    argmax_kernel<<<NBLK, 256, 0, stream>>>(xq, best);
    loss_kernel<<<NROWS / 4, 256, 0, stream>>>(a, b, invn, best, terms);
    reduce_kernel<<<1, 1024, 0, stream>>>(terms, out);
}